// Round 1
// baseline (1608.546 us; speedup 1.0000x reference)
//
#include <hip/hip_runtime.h>

// ANI-1 per-species MLP on AEVs, fused fp32 baseline.
// Layers: 384 -> 160 -> 128 -> 96 -> 1, CELU(alpha=0.1) between.
// One block per atom (512 blocks), 256 threads = 4 waves.
// lane (0..63) = molecule within a 64-molecule chunk; wave q owns a
// contiguous quarter of output neurons -> weight reads are wave-uniform
// (scalar loads), x reads from LDS, fp32 accumulators in VGPRs.

#define AEV   384
#define H0    160
#define H1    128
#define H2    96
#define NMOL  128
#define NATOM 512
#define CHUNK 64

__device__ __forceinline__ float celu_f(float x) {
    // celu(x, 0.1) = max(x,0) + min(0.1*expm1(10x), 0)
    return fmaxf(x, 0.0f) + fminf(0.1f * expm1f(x * 10.0f), 0.0f);
}

__global__ __launch_bounds__(256) void ani_mlp_kernel(
    const float* __restrict__ aev, const int* __restrict__ species,
    const float* __restrict__ W0, const float* __restrict__ b0,
    const float* __restrict__ W1, const float* __restrict__ b1,
    const float* __restrict__ W2, const float* __restrict__ b2,
    const float* __restrict__ W3, const float* __restrict__ b3,
    float* __restrict__ partial)
{
    // xbuf: X chunk [64][385] (pad 385: (lane*385+i)%32 = (lane+i)%32 -> 2-way, free)
    // ybuf: Y0 as [160][64], later reused as Y2 [96][64]
    // Y1 [128][64] reuses the xbuf region after L0 consumed X.
    __shared__ float xbuf[CHUNK * 385];   // 98560 B
    __shared__ float ybuf[H0 * CHUNK];    // 40960 B   (total 139520 B < 160 KiB)

    const int a    = blockIdx.x;
    const int tid  = threadIdx.x;
    const int lane = tid & 63;
    const int q    = __builtin_amdgcn_readfirstlane(tid >> 6);
    const int s    = __builtin_amdgcn_readfirstlane(species[a]);

    const float* W0s = W0 + (size_t)s * H0 * AEV;
    const float* b0s = b0 + s * H0;
    const float* W1s = W1 + (size_t)s * H1 * H0;
    const float* b1s = b1 + s * H1;
    const float* W2s = W2 + (size_t)s * H2 * H1;
    const float* b2s = b2 + s * H2;
    const float* W3s = W3 + (size_t)s * H2;  // [1][96]
    const float  bb3 = b3[s];

    float* y1 = xbuf;  // [H1][CHUNK], alias of xbuf (X dead by then)

    for (int chunk = 0; chunk < NMOL / CHUNK; ++chunk) {
        const int mb = chunk * CHUNK;

        // ---- stage X chunk: [64 molecules][384] -> xbuf[r*385 + i]
        for (int idx = tid; idx < CHUNK * (AEV / 4); idx += 256) {
            const int r  = idx / (AEV / 4);
            const int c4 = idx % (AEV / 4);
            const float4 v = reinterpret_cast<const float4*>(
                aev + ((size_t)(mb + r) * NATOM + a) * AEV)[c4];
            float* d = &xbuf[r * 385 + c4 * 4];
            d[0] = v.x; d[1] = v.y; d[2] = v.z; d[3] = v.w;
        }
        __syncthreads();

        // ---- L0: 384 -> 160, wave q computes o in [q*40, q*40+40)
        {
            const int o0 = q * (H0 / 4);
            float acc[H0 / 4];
            #pragma unroll
            for (int j = 0; j < H0 / 4; ++j) acc[j] = b0s[o0 + j];
            #pragma unroll 4
            for (int i = 0; i < AEV; ++i) {
                const float x = xbuf[lane * 385 + i];
                #pragma unroll
                for (int j = 0; j < H0 / 4; ++j)
                    acc[j] = fmaf(W0s[(size_t)(o0 + j) * AEV + i], x, acc[j]);
            }
            #pragma unroll
            for (int j = 0; j < H0 / 4; ++j)
                ybuf[(o0 + j) * CHUNK + lane] = celu_f(acc[j]);
        }
        __syncthreads();

        // ---- L1: 160 -> 128, writes into xbuf region (X dead)
        {
            const int o0 = q * (H1 / 4);
            float acc[H1 / 4];
            #pragma unroll
            for (int j = 0; j < H1 / 4; ++j) acc[j] = b1s[o0 + j];
            #pragma unroll 4
            for (int i = 0; i < H0; ++i) {
                const float x = ybuf[i * CHUNK + lane];
                #pragma unroll
                for (int j = 0; j < H1 / 4; ++j)
                    acc[j] = fmaf(W1s[(size_t)(o0 + j) * H0 + i], x, acc[j]);
            }
            #pragma unroll
            for (int j = 0; j < H1 / 4; ++j)
                y1[(o0 + j) * CHUNK + lane] = celu_f(acc[j]);
        }
        __syncthreads();

        // ---- L2: 128 -> 96, writes into ybuf region (Y0 dead)
        {
            const int o0 = q * (H2 / 4);
            float acc[H2 / 4];
            #pragma unroll
            for (int j = 0; j < H2 / 4; ++j) acc[j] = b2s[o0 + j];
            #pragma unroll 4
            for (int i = 0; i < H1; ++i) {
                const float x = y1[i * CHUNK + lane];
                #pragma unroll
                for (int j = 0; j < H2 / 4; ++j)
                    acc[j] = fmaf(W2s[(size_t)(o0 + j) * H1 + i], x, acc[j]);
            }
            #pragma unroll
            for (int j = 0; j < H2 / 4; ++j)
                ybuf[(o0 + j) * CHUNK + lane] = celu_f(acc[j]);
        }
        __syncthreads();

        // ---- L3: 96 -> 1 (wave 0 only; trivial cost)
        if (tid < CHUNK) {
            float accv = bb3;
            #pragma unroll 4
            for (int i = 0; i < H2; ++i)
                accv = fmaf(W3s[i], ybuf[i * CHUNK + tid], accv);
            partial[(size_t)a * NMOL + mb + tid] = accv;
        }
        __syncthreads();  // protect xbuf/ybuf before next chunk
    }
}

__global__ __launch_bounds__(128) void reduce_kernel(
    const float* __restrict__ partial, float* __restrict__ out)
{
    const int b = threadIdx.x;  // 128 threads, one per molecule
    float s = 0.0f;
    #pragma unroll 8
    for (int a = 0; a < NATOM; ++a) s += partial[(size_t)a * NMOL + b];
    out[b] = s;
}

extern "C" void kernel_launch(void* const* d_in, const int* in_sizes, int n_in,
                              void* d_out, int out_size, void* d_ws, size_t ws_size,
                              hipStream_t stream) {
    const float* aev     = (const float*)d_in[0];
    const int*   species = (const int*)  d_in[1];
    const float* W0 = (const float*)d_in[2];
    const float* b0 = (const float*)d_in[3];
    const float* W1 = (const float*)d_in[4];
    const float* b1 = (const float*)d_in[5];
    const float* W2 = (const float*)d_in[6];
    const float* b2 = (const float*)d_in[7];
    const float* W3 = (const float*)d_in[8];
    const float* b3 = (const float*)d_in[9];
    float* out     = (float*)d_out;
    float* partial = (float*)d_ws;   // NATOM * NMOL floats = 256 KiB

    ani_mlp_kernel<<<NATOM, 256, 0, stream>>>(aev, species,
                                              W0, b0, W1, b1, W2, b2, W3, b3,
                                              partial);
    reduce_kernel<<<1, NMOL, 0, stream>>>(partial, out);
}

// Round 2
// 78.079 us; speedup vs baseline: 20.6014x; 20.6014x over previous
//
#include <hip/hip_runtime.h>

// ANI-1 per-species MLP, MFMA split-bf16 version.
// Per atom: Y = X[128 mol x K] * W^T, layers 384->160->128->96->1, CELU(0.1).
// Split precision: every fp32 value v = hi(bf16) + lo(bf16); products via
// 3 MFMAs (hh, hl, lh) with fp32 accumulation -> ~fp32 accuracy.
// Block = 512 threads (8 waves, 2 M-groups x 4 N-groups), grid = 512 atoms.
// W pre-split+swizzled into frag order in d_ws by prep kernel each launch.

typedef float f32x4 __attribute__((ext_vector_type(4)));
typedef short s16x8 __attribute__((ext_vector_type(8)));

#define NMOL   128
#define NATOM  512
#define AEV    384

// Wp element offsets (bf16 units)
#define PL0    61440            // 160*384
#define PL1    20480            // 128*160
#define PL2    12288            // 96*128
#define BASE0  0
#define BASE1  491520           // 4*2*PL0
#define BASE2  655360           // BASE1 + 4*2*PL1
#define WP_BYTE_OFF 262144      // partial buffer (512*128*4) comes first in d_ws

__device__ __forceinline__ ushort f2bf(float f) {
    uint u = __float_as_uint(f);
    return (ushort)((u + 0x7fffu + ((u >> 16) & 1u)) >> 16);
}
__device__ __forceinline__ float bf2f(ushort h) {
    return __uint_as_float(((uint)h) << 16);
}
__device__ __forceinline__ float celu_f(float v) {
    // celu(v,0.1)=max(v,0)+min(0.1*(exp(10v)-1),0); __expf abs err ~1e-8 here
    return fmaxf(v, 0.0f) + fminf(0.1f * (__expf(10.0f * v) - 1.0f), 0.0f);
}
__device__ __forceinline__ f32x4 mfma3(s16x8 ah, s16x8 al, s16x8 bh, s16x8 bl, f32x4 c) {
    c = __builtin_amdgcn_mfma_f32_16x16x32_bf16(ah, bh, c, 0, 0, 0);
    c = __builtin_amdgcn_mfma_f32_16x16x32_bf16(ah, bl, c, 0, 0, 0);
    c = __builtin_amdgcn_mfma_f32_16x16x32_bf16(al, bh, c, 0, 0, 0);
    return c;
}

// ---- prep: split W0..W2 into frag-ordered hi/lo bf16 planes in d_ws ----
__global__ __launch_bounds__(256) void prep_kernel(
    const float* __restrict__ W0, const float* __restrict__ W1,
    const float* __restrict__ W2, ushort* __restrict__ Wp)
{
    const int idx = blockIdx.x * 256 + threadIdx.x;   // grid sized exactly 376832
    int n, k, KS, plane;
    size_t base;
    float f;
    if (idx < 245760) {                       // L0: [4][160][384]
        const int s = idx / PL0, r = idx % PL0;
        n = r / 384; k = r % 384; KS = 12; plane = PL0;
        f = W0[idx];
        base = BASE0 + (size_t)s * 2 * PL0;
    } else if (idx < 327680) {                // L1: [4][128][160]
        const int i2 = idx - 245760;
        const int s = i2 / PL1, r = i2 % PL1;
        n = r / 160; k = r % 160; KS = 5; plane = PL1;
        f = W1[i2];
        base = BASE1 + (size_t)s * 2 * PL1;
    } else {                                  // L2: [4][96][128]
        const int i2 = idx - 327680;
        const int s = i2 / PL2, r = i2 % PL2;
        n = r / 128; k = r % 128; KS = 4; plane = PL2;
        f = W2[i2];
        base = BASE2 + (size_t)s * 2 * PL2;
    }
    // frag order: lane l holds B[k=(l>>4)*8+j][n=l&15] for kstep, fragN
    const size_t fo = (size_t)((((n >> 4) * KS + (k >> 5)) * 64
                                + ((k & 31) >> 3) * 16 + (n & 15)) * 8 + (k & 7));
    const ushort h = f2bf(f);
    const ushort l = f2bf(f - bf2f(h));
    Wp[base + fo] = h;
    Wp[base + plane + fo] = l;
}

// ---- generic resident-A layer: M=128, N=NF*16, K=KS*32 ----
template <int KS, int NF>
__device__ __forceinline__ void layer_gemm(
    const ushort* __restrict__ Ah, const ushort* __restrict__ Al, const int lda,
    const ushort* __restrict__ Bh, const ushort* __restrict__ Bl,
    const float* __restrict__ bias,
    ushort* __restrict__ Ch, ushort* __restrict__ Cl, const int ldc,
    const int mgrp, const int ngrp, const int lane)
{
    f32x4 acc[4][3];
    const f32x4 zero = {0.f, 0.f, 0.f, 0.f};
    #pragma unroll
    for (int mf = 0; mf < 4; ++mf)
        #pragma unroll
        for (int t = 0; t < 3; ++t) acc[mf][t] = zero;

    const int arow = mgrp * 64 + (lane & 15);
    const int akoff = (lane >> 4) * 8;

    #pragma unroll
    for (int ks = 0; ks < KS; ++ks) {
        s16x8 ah[4], al[4];
        #pragma unroll
        for (int mf = 0; mf < 4; ++mf) {
            const int ao = (arow + mf * 16) * lda + ks * 32 + akoff;
            ah[mf] = *(const s16x8*)(Ah + ao);
            al[mf] = *(const s16x8*)(Al + ao);
        }
        #pragma unroll
        for (int t = 0; t < 3; ++t) {
            const int nf = ngrp + 4 * t;
            if (nf < NF) {
                const int bo = ((nf * KS + ks) * 64 + lane) * 8;
                const s16x8 bh = *(const s16x8*)(Bh + bo);
                const s16x8 bl = *(const s16x8*)(Bl + bo);
                #pragma unroll
                for (int mf = 0; mf < 4; ++mf)
                    acc[mf][t] = mfma3(ah[mf], al[mf], bh, bl, acc[mf][t]);
            }
        }
    }
    // epilogue: bias + CELU + split -> LDS
    #pragma unroll
    for (int t = 0; t < 3; ++t) {
        const int nf = ngrp + 4 * t;
        if (nf < NF) {
            const int n = nf * 16 + (lane & 15);
            const float bv = bias[n];
            #pragma unroll
            for (int mf = 0; mf < 4; ++mf) {
                #pragma unroll
                for (int r = 0; r < 4; ++r) {
                    const int row = mgrp * 64 + mf * 16 + (lane >> 4) * 4 + r;
                    const float v = celu_f(acc[mf][t][r] + bv);
                    const ushort h = f2bf(v);
                    const ushort lo2 = f2bf(v - bf2f(h));
                    Ch[row * ldc + n] = h;
                    Cl[row * ldc + n] = lo2;
                }
            }
        }
    }
}

__global__ __launch_bounds__(512, 2) void ani_mfma_kernel(
    const float* __restrict__ aev, const int* __restrict__ species,
    const ushort* __restrict__ Wp,
    const float* __restrict__ b0, const float* __restrict__ b1,
    const float* __restrict__ b2,
    const float* __restrict__ W3, const float* __restrict__ b3,
    float* __restrict__ partial)
{
    __shared__ __align__(16) ushort xbuf[2 * 128 * 136];   //  69.6 KB: X tiles -> Y1 -> red
    __shared__ __align__(16) ushort ybuf[2 * 128 * 168];   //  86.0 KB: Y0 -> Y2

    const int a    = blockIdx.x;
    const int tid  = threadIdx.x;
    const int lane = tid & 63;
    const int wid  = tid >> 6;
    const int mgrp = wid >> 2;    // 0..1
    const int ngrp = wid & 3;     // 0..3
    const int s    = species[a];

    ushort* Xh  = xbuf;             ushort* Xl  = xbuf + 128 * 136;
    ushort* Y0h = ybuf;             ushort* Y0l = ybuf + 128 * 168;
    ushort* Y1h = xbuf;             ushort* Y1l = xbuf + 128 * 136;
    ushort* Y2h = ybuf;             ushort* Y2l = ybuf + 128 * 104;

    const ushort* Bh0 = Wp + BASE0 + (size_t)s * 2 * PL0;  const ushort* Bl0 = Bh0 + PL0;
    const ushort* Bh1 = Wp + BASE1 + (size_t)s * 2 * PL1;  const ushort* Bl1 = Bh1 + PL1;
    const ushort* Bh2 = Wp + BASE2 + (size_t)s * 2 * PL2;  const ushort* Bl2 = Bh2 + PL2;
    const float* b0s = b0 + s * 160;
    const float* b1s = b1 + s * 128;
    const float* b2s = b2 + s * 96;
    const float* w3s = W3 + s * 96;
    const float  bb3 = b3[s];

    // ================= L0: 384 -> 160, K-tiled X staging =================
    f32x4 acc[4][3];
    const f32x4 zero = {0.f, 0.f, 0.f, 0.f};
    #pragma unroll
    for (int mf = 0; mf < 4; ++mf)
        #pragma unroll
        for (int t = 0; t < 3; ++t) acc[mf][t] = zero;

    float4 rv[8];
    #pragma unroll
    for (int p = 0; p < 8; ++p) {     // prefetch tile 0
        const int ix = tid + p * 512;
        rv[p] = *(const float4*)(aev + ((size_t)(ix >> 5) * NATOM + a) * AEV + (ix & 31) * 4);
    }

    for (int tile = 0; tile < 3; ++tile) {
        // write staged regs (hi/lo split) into LDS
        #pragma unroll
        for (int p = 0; p < 8; ++p) {
            const int ix = tid + p * 512;
            const int mol = ix >> 5, c4 = ix & 31;
            const float4 v = rv[p];
            const ushort h0 = f2bf(v.x), h1 = f2bf(v.y), h2 = f2bf(v.z), h3 = f2bf(v.w);
            const ushort l0 = f2bf(v.x - bf2f(h0)), l1 = f2bf(v.y - bf2f(h1));
            const ushort l2 = f2bf(v.z - bf2f(h2)), l3 = f2bf(v.w - bf2f(h3));
            uint2 ph, pl;
            ph.x = (uint)h0 | ((uint)h1 << 16);  ph.y = (uint)h2 | ((uint)h3 << 16);
            pl.x = (uint)l0 | ((uint)l1 << 16);  pl.y = (uint)l2 | ((uint)l3 << 16);
            *(uint2*)(Xh + mol * 136 + c4 * 4) = ph;
            *(uint2*)(Xl + mol * 136 + c4 * 4) = pl;
        }
        __syncthreads();
        if (tile < 2) {               // prefetch next tile during compute
            #pragma unroll
            for (int p = 0; p < 8; ++p) {
                const int ix = tid + p * 512;
                rv[p] = *(const float4*)(aev + ((size_t)(ix >> 5) * NATOM + a) * AEV
                                         + (tile + 1) * 128 + (ix & 31) * 4);
            }
        }
        #pragma unroll
        for (int ks = 0; ks < 4; ++ks) {
            const int gks = tile * 4 + ks;
            s16x8 ah[4], al[4];
            #pragma unroll
            for (int mf = 0; mf < 4; ++mf) {
                const int ao = (mgrp * 64 + mf * 16 + (lane & 15)) * 136
                               + ks * 32 + (lane >> 4) * 8;
                ah[mf] = *(const s16x8*)(Xh + ao);
                al[mf] = *(const s16x8*)(Xl + ao);
            }
            #pragma unroll
            for (int t = 0; t < 3; ++t) {
                const int nf = ngrp + 4 * t;
                if (nf < 10) {
                    const int bo = ((nf * 12 + gks) * 64 + lane) * 8;
                    const s16x8 bh = *(const s16x8*)(Bh0 + bo);
                    const s16x8 bl = *(const s16x8*)(Bl0 + bo);
                    #pragma unroll
                    for (int mf = 0; mf < 4; ++mf)
                        acc[mf][t] = mfma3(ah[mf], al[mf], bh, bl, acc[mf][t]);
                }
            }
        }
        __syncthreads();
    }
    // L0 epilogue -> Y0 (ld 168)
    #pragma unroll
    for (int t = 0; t < 3; ++t) {
        const int nf = ngrp + 4 * t;
        if (nf < 10) {
            const int n = nf * 16 + (lane & 15);
            const float bv = b0s[n];
            #pragma unroll
            for (int mf = 0; mf < 4; ++mf) {
                #pragma unroll
                for (int r = 0; r < 4; ++r) {
                    const int row = mgrp * 64 + mf * 16 + (lane >> 4) * 4 + r;
                    const float v = celu_f(acc[mf][t][r] + bv);
                    const ushort h = f2bf(v);
                    const ushort lo2 = f2bf(v - bf2f(h));
                    Y0h[row * 168 + n] = h;
                    Y0l[row * 168 + n] = lo2;
                }
            }
        }
    }
    __syncthreads();

    // ================= L1: 160 -> 128 =================
    layer_gemm<5, 8>(Y0h, Y0l, 168, Bh1, Bl1, b1s, Y1h, Y1l, 136, mgrp, ngrp, lane);
    __syncthreads();

    // ================= L2: 128 -> 96 =================
    layer_gemm<4, 6>(Y1h, Y1l, 136, Bh2, Bl2, b2s, Y2h, Y2l, 104, mgrp, ngrp, lane);
    __syncthreads();

    // ================= L3: 96 -> 1 (fp32 vector) =================
    {
        float* red = (float*)xbuf;   // Y1 dead
        const int m = tid & 127;
        const int q = tid >> 7;      // 0..3, each handles 24 of 96 inputs
        float accv = 0.f;
        #pragma unroll
        for (int ii = 0; ii < 24; ++ii) {
            const int i = q * 24 + ii;
            const float y = bf2f(Y2h[m * 104 + i]) + bf2f(Y2l[m * 104 + i]);
            accv = fmaf(w3s[i], y, accv);
        }
        red[q * 128 + m] = accv;
        __syncthreads();
        if (tid < 128) {
            const float sm = red[tid] + red[128 + tid] + red[256 + tid] + red[384 + tid] + bb3;
            partial[(size_t)a * NMOL + tid] = sm;
        }
    }
}

__global__ __launch_bounds__(256) void reduce_kernel(
    const float* __restrict__ partial, float* __restrict__ out)
{
    __shared__ float red[256];
    const int m = blockIdx.x;       // molecule
    const int t = threadIdx.x;
    float sv = partial[(size_t)t * NMOL + m] + partial[(size_t)(t + 256) * NMOL + m];
    red[t] = sv;
    __syncthreads();
    #pragma unroll
    for (int w = 128; w > 0; w >>= 1) {
        if (t < w) red[t] += red[t + w];
        __syncthreads();
    }
    if (t == 0) out[m] = red[0];
}

extern "C" void kernel_launch(void* const* d_in, const int* in_sizes, int n_in,
                              void* d_out, int out_size, void* d_ws, size_t ws_size,
                              hipStream_t stream) {
    const float* aev     = (const float*)d_in[0];
    const int*   species = (const int*)  d_in[1];
    const float* W0 = (const float*)d_in[2];
    const float* b0 = (const float*)d_in[3];
    const float* W1 = (const float*)d_in[4];
    const float* b1 = (const float*)d_in[5];
    const float* W2 = (const float*)d_in[6];
    const float* b2 = (const float*)d_in[7];
    const float* W3 = (const float*)d_in[8];
    const float* b3 = (const float*)d_in[9];
    float* out     = (float*)d_out;
    float* partial = (float*)d_ws;                               // 256 KiB
    ushort* Wp     = (ushort*)((char*)d_ws + WP_BYTE_OFF);       // ~1.5 MiB

    prep_kernel<<<1472, 256, 0, stream>>>(W0, W1, W2, Wp);
    ani_mfma_kernel<<<NATOM, 512, 0, stream>>>(aev, species, Wp,
                                               b0, b1, b2, W3, b3, partial);
    reduce_kernel<<<NMOL, 256, 0, stream>>>(partial, out);
}

// Round 3
// 68.116 us; speedup vs baseline: 23.6146x; 1.1463x over previous
//
#include <hip/hip_runtime.h>

// ANI-1 per-species MLP, MFMA split-bf16, v3: M-tile 64 -> 2 blocks/CU.
// Per (atom, mol-half): Y = X[64 x K] * W^T, layers 384->160->128->96->1.
// Split precision: v = hi(bf16) + lo(bf16); 3 MFMAs (hh,hl,lh), fp32 acc.
// Block = 512 threads (8 waves, 2 M-groups x 4 N-groups), grid = 1024.
// LDS 77.8 KB -> 2 blocks/CU (16 waves/CU) for latency hiding.

typedef float f32x4 __attribute__((ext_vector_type(4)));
typedef short s16x8 __attribute__((ext_vector_type(8)));

#define NMOL   128
#define NATOM  512
#define AEV    384
#define MT     64               // molecules per block

// Wp element offsets (bf16 units)
#define PL0    61440            // 160*384
#define PL1    20480            // 128*160
#define PL2    12288            // 96*128
#define BASE0  0
#define BASE1  491520           // 4*2*PL0
#define BASE2  655360           // BASE1 + 4*2*PL1
#define WP_BYTE_OFF 262144      // partial buffer (512*128*4) comes first in d_ws

__device__ __forceinline__ ushort f2bf(float f) {
    uint u = __float_as_uint(f);
    return (ushort)((u + 0x7fffu + ((u >> 16) & 1u)) >> 16);
}
__device__ __forceinline__ float bf2f(ushort h) {
    return __uint_as_float(((uint)h) << 16);
}
__device__ __forceinline__ float celu_f(float v) {
    return fmaxf(v, 0.0f) + fminf(0.1f * (__expf(10.0f * v) - 1.0f), 0.0f);
}
__device__ __forceinline__ f32x4 mfma3(s16x8 ah, s16x8 al, s16x8 bh, s16x8 bl, f32x4 c) {
    c = __builtin_amdgcn_mfma_f32_16x16x32_bf16(ah, bh, c, 0, 0, 0);
    c = __builtin_amdgcn_mfma_f32_16x16x32_bf16(ah, bl, c, 0, 0, 0);
    c = __builtin_amdgcn_mfma_f32_16x16x32_bf16(al, bh, c, 0, 0, 0);
    return c;
}

// ---- prep: split W0..W2 into frag-ordered hi/lo bf16 planes in d_ws ----
__global__ __launch_bounds__(256) void prep_kernel(
    const float* __restrict__ W0, const float* __restrict__ W1,
    const float* __restrict__ W2, ushort* __restrict__ Wp)
{
    const int idx = blockIdx.x * 256 + threadIdx.x;   // grid sized exactly 376832
    int n, k, KS, plane;
    size_t base;
    float f;
    if (idx < 245760) {                       // L0: [4][160][384]
        const int s = idx / PL0, r = idx % PL0;
        n = r / 384; k = r % 384; KS = 12; plane = PL0;
        f = W0[idx];
        base = BASE0 + (size_t)s * 2 * PL0;
    } else if (idx < 327680) {                // L1: [4][128][160]
        const int i2 = idx - 245760;
        const int s = i2 / PL1, r = i2 % PL1;
        n = r / 160; k = r % 160; KS = 5; plane = PL1;
        f = W1[i2];
        base = BASE1 + (size_t)s * 2 * PL1;
    } else {                                  // L2: [4][96][128]
        const int i2 = idx - 327680;
        const int s = i2 / PL2, r = i2 % PL2;
        n = r / 128; k = r % 128; KS = 4; plane = PL2;
        f = W2[i2];
        base = BASE2 + (size_t)s * 2 * PL2;
    }
    // frag order: lane l holds B[k=(l>>4)*8+j][n=l&15] for (kstep, fragN)
    const size_t fo = (size_t)((((n >> 4) * KS + (k >> 5)) * 64
                                + ((k & 31) >> 3) * 16 + (n & 15)) * 8 + (k & 7));
    const ushort h = f2bf(f);
    const ushort l = f2bf(f - bf2f(h));
    Wp[base + fo] = h;
    Wp[base + plane + fo] = l;
}

// ---- generic resident-A layer: M=64 (2 mgrp x 2 frag), N=NF*16, K=KS*32 ----
template <int KS, int NF>
__device__ __forceinline__ void layer_gemm(
    const ushort* __restrict__ Ah, const ushort* __restrict__ Al, const int lda,
    const ushort* __restrict__ Bh, const ushort* __restrict__ Bl,
    const float* __restrict__ bias,
    ushort* __restrict__ Ch, ushort* __restrict__ Cl, const int ldc,
    const int mgrp, const int ngrp, const int lane)
{
    f32x4 acc[2][3];
    const f32x4 zero = {0.f, 0.f, 0.f, 0.f};
    #pragma unroll
    for (int mf = 0; mf < 2; ++mf)
        #pragma unroll
        for (int t = 0; t < 3; ++t) acc[mf][t] = zero;

    const int arow  = mgrp * 32 + (lane & 15);
    const int akoff = (lane >> 4) * 8;

    #pragma unroll
    for (int ks = 0; ks < KS; ++ks) {
        s16x8 ah[2], al[2];
        #pragma unroll
        for (int mf = 0; mf < 2; ++mf) {
            const int ao = (arow + mf * 16) * lda + ks * 32 + akoff;
            ah[mf] = *(const s16x8*)(Ah + ao);
            al[mf] = *(const s16x8*)(Al + ao);
        }
        #pragma unroll
        for (int t = 0; t < 3; ++t) {
            const int nf = ngrp + 4 * t;
            if (nf < NF) {
                const int bo = ((nf * KS + ks) * 64 + lane) * 8;
                const s16x8 bh = *(const s16x8*)(Bh + bo);
                const s16x8 bl = *(const s16x8*)(Bl + bo);
                #pragma unroll
                for (int mf = 0; mf < 2; ++mf)
                    acc[mf][t] = mfma3(ah[mf], al[mf], bh, bl, acc[mf][t]);
            }
        }
    }
    // epilogue: bias + CELU + split -> LDS
    #pragma unroll
    for (int t = 0; t < 3; ++t) {
        const int nf = ngrp + 4 * t;
        if (nf < NF) {
            const int n = nf * 16 + (lane & 15);
            const float bv = bias[n];
            #pragma unroll
            for (int mf = 0; mf < 2; ++mf) {
                #pragma unroll
                for (int r = 0; r < 4; ++r) {
                    const int row = mgrp * 32 + mf * 16 + (lane >> 4) * 4 + r;
                    const float v = celu_f(acc[mf][t][r] + bv);
                    const ushort h = f2bf(v);
                    const ushort lo2 = f2bf(v - bf2f(h));
                    Ch[row * ldc + n] = h;
                    Cl[row * ldc + n] = lo2;
                }
            }
        }
    }
}

__global__ __launch_bounds__(512, 2) void ani_mfma_kernel(
    const float* __restrict__ aev, const int* __restrict__ species,
    const ushort* __restrict__ Wp,
    const float* __restrict__ b0, const float* __restrict__ b1,
    const float* __restrict__ b2,
    const float* __restrict__ W3, const float* __restrict__ b3,
    float* __restrict__ partial)
{
    __shared__ __align__(16) ushort xbuf[2 * MT * 136];   // 34816 B: X tiles -> Y1 -> red
    __shared__ __align__(16) ushort ybuf[2 * MT * 168];   // 43008 B: Y0 -> Y2

    const int bid  = blockIdx.x;
    const int a    = bid >> 1;          // atom
    const int half = bid & 1;           // which 64-molecule half
    const int tid  = threadIdx.x;
    const int lane = tid & 63;
    const int wid  = tid >> 6;
    const int mgrp = wid >> 2;          // 0..1 (rows mgrp*32 .. +31)
    const int ngrp = wid & 3;           // 0..3
    const int s    = species[a];

    ushort* Xh  = xbuf;             ushort* Xl  = xbuf + MT * 136;
    ushort* Y0h = ybuf;             ushort* Y0l = ybuf + MT * 168;
    ushort* Y1h = xbuf;             ushort* Y1l = xbuf + MT * 136;
    ushort* Y2h = ybuf;             ushort* Y2l = ybuf + MT * 104;

    const ushort* Bh0 = Wp + BASE0 + (size_t)s * 2 * PL0;  const ushort* Bl0 = Bh0 + PL0;
    const ushort* Bh1 = Wp + BASE1 + (size_t)s * 2 * PL1;  const ushort* Bl1 = Bh1 + PL1;
    const ushort* Bh2 = Wp + BASE2 + (size_t)s * 2 * PL2;  const ushort* Bl2 = Bh2 + PL2;
    const float* b0s = b0 + s * 160;
    const float* b1s = b1 + s * 128;
    const float* b2s = b2 + s * 96;
    const float* w3s = W3 + s * 96;
    const float  bb3 = b3[s];

    // ================= L0: 384 -> 160, K-tiled X staging =================
    f32x4 acc[2][3];
    const f32x4 zero = {0.f, 0.f, 0.f, 0.f};
    #pragma unroll
    for (int mf = 0; mf < 2; ++mf)
        #pragma unroll
        for (int t = 0; t < 3; ++t) acc[mf][t] = zero;

    float4 rv[4];
    #pragma unroll
    for (int p = 0; p < 4; ++p) {     // prefetch tile 0: [64 mol][128 k]
        const int ix = tid + p * 512;
        const int gmol = half * MT + (ix >> 5);
        rv[p] = *(const float4*)(aev + ((size_t)gmol * NATOM + a) * AEV + (ix & 31) * 4);
    }

    for (int tile = 0; tile < 3; ++tile) {
        // write staged regs (hi/lo split) into LDS
        #pragma unroll
        for (int p = 0; p < 4; ++p) {
            const int ix = tid + p * 512;
            const int mol = ix >> 5, c4 = ix & 31;
            const float4 v = rv[p];
            const ushort h0 = f2bf(v.x), h1 = f2bf(v.y), h2 = f2bf(v.z), h3 = f2bf(v.w);
            const ushort l0 = f2bf(v.x - bf2f(h0)), l1 = f2bf(v.y - bf2f(h1));
            const ushort l2 = f2bf(v.z - bf2f(h2)), l3 = f2bf(v.w - bf2f(h3));
            uint2 ph, pl;
            ph.x = (uint)h0 | ((uint)h1 << 16);  ph.y = (uint)h2 | ((uint)h3 << 16);
            pl.x = (uint)l0 | ((uint)l1 << 16);  pl.y = (uint)l2 | ((uint)l3 << 16);
            *(uint2*)(Xh + mol * 136 + c4 * 4) = ph;
            *(uint2*)(Xl + mol * 136 + c4 * 4) = pl;
        }
        __syncthreads();
        if (tile < 2) {               // prefetch next tile during compute
            #pragma unroll
            for (int p = 0; p < 4; ++p) {
                const int ix = tid + p * 512;
                const int gmol = half * MT + (ix >> 5);
                rv[p] = *(const float4*)(aev + ((size_t)gmol * NATOM + a) * AEV
                                         + (tile + 1) * 128 + (ix & 31) * 4);
            }
        }
        #pragma unroll
        for (int ks = 0; ks < 4; ++ks) {
            const int gks = tile * 4 + ks;
            s16x8 ah[2], al[2];
            #pragma unroll
            for (int mf = 0; mf < 2; ++mf) {
                const int ao = (mgrp * 32 + mf * 16 + (lane & 15)) * 136
                               + ks * 32 + (lane >> 4) * 8;
                ah[mf] = *(const s16x8*)(Xh + ao);
                al[mf] = *(const s16x8*)(Xl + ao);
            }
            #pragma unroll
            for (int t = 0; t < 3; ++t) {
                const int nf = ngrp + 4 * t;
                if (nf < 10) {
                    const int bo = ((nf * 12 + gks) * 64 + lane) * 8;
                    const s16x8 bh = *(const s16x8*)(Bh0 + bo);
                    const s16x8 bl = *(const s16x8*)(Bl0 + bo);
                    #pragma unroll
                    for (int mf = 0; mf < 2; ++mf)
                        acc[mf][t] = mfma3(ah[mf], al[mf], bh, bl, acc[mf][t]);
                }
            }
        }
        __syncthreads();
    }
    // L0 epilogue -> Y0 (ld 168)
    #pragma unroll
    for (int t = 0; t < 3; ++t) {
        const int nf = ngrp + 4 * t;
        if (nf < 10) {
            const int n = nf * 16 + (lane & 15);
            const float bv = b0s[n];
            #pragma unroll
            for (int mf = 0; mf < 2; ++mf) {
                #pragma unroll
                for (int r = 0; r < 4; ++r) {
                    const int row = mgrp * 32 + mf * 16 + (lane >> 4) * 4 + r;
                    const float v = celu_f(acc[mf][t][r] + bv);
                    const ushort h = f2bf(v);
                    const ushort lo2 = f2bf(v - bf2f(h));
                    Y0h[row * 168 + n] = h;
                    Y0l[row * 168 + n] = lo2;
                }
            }
        }
    }
    __syncthreads();

    // ================= L1: 160 -> 128 =================
    layer_gemm<5, 8>(Y0h, Y0l, 168, Bh1, Bl1, b1s, Y1h, Y1l, 136, mgrp, ngrp, lane);
    __syncthreads();

    // ================= L2: 128 -> 96 =================
    layer_gemm<4, 6>(Y1h, Y1l, 136, Bh2, Bl2, b2s, Y2h, Y2l, 104, mgrp, ngrp, lane);
    __syncthreads();

    // ================= L3: 96 -> 1 (fp32 vector) =================
    {
        float* red = (float*)xbuf;   // Y1 dead
        const int m = tid & (MT - 1);
        const int q = tid >> 6;      // 0..7, each handles 12 of 96 inputs
        float accv = 0.f;
        #pragma unroll
        for (int ii = 0; ii < 12; ++ii) {
            const int i = q * 12 + ii;
            const float y = bf2f(Y2h[m * 104 + i]) + bf2f(Y2l[m * 104 + i]);
            accv = fmaf(w3s[i], y, accv);
        }
        red[q * MT + m] = accv;
        __syncthreads();
        if (tid < MT) {
            float sm = bb3;
            #pragma unroll
            for (int qq = 0; qq < 8; ++qq) sm += red[qq * MT + tid];
            partial[(size_t)a * NMOL + half * MT + tid] = sm;
        }
    }
}

__global__ __launch_bounds__(256) void reduce_kernel(
    const float* __restrict__ partial, float* __restrict__ out)
{
    __shared__ float red[256];
    const int m = blockIdx.x;       // molecule
    const int t = threadIdx.x;
    float sv = partial[(size_t)t * NMOL + m] + partial[(size_t)(t + 256) * NMOL + m];
    red[t] = sv;
    __syncthreads();
    #pragma unroll
    for (int w = 128; w > 0; w >>= 1) {
        if (t < w) red[t] += red[t + w];
        __syncthreads();
    }
    if (t == 0) out[m] = red[0];
}

extern "C" void kernel_launch(void* const* d_in, const int* in_sizes, int n_in,
                              void* d_out, int out_size, void* d_ws, size_t ws_size,
                              hipStream_t stream) {
    const float* aev     = (const float*)d_in[0];
    const int*   species = (const int*)  d_in[1];
    const float* W0 = (const float*)d_in[2];
    const float* b0 = (const float*)d_in[3];
    const float* W1 = (const float*)d_in[4];
    const float* b1 = (const float*)d_in[5];
    const float* W2 = (const float*)d_in[6];
    const float* b2 = (const float*)d_in[7];
    const float* W3 = (const float*)d_in[8];
    const float* b3 = (const float*)d_in[9];
    float* out     = (float*)d_out;
    float* partial = (float*)d_ws;                               // 256 KiB
    ushort* Wp     = (ushort*)((char*)d_ws + WP_BYTE_OFF);       // ~1.5 MiB

    prep_kernel<<<1472, 256, 0, stream>>>(W0, W1, W2, Wp);
    ani_mfma_kernel<<<NATOM * 2, 512, 0, stream>>>(aev, species, Wp,
                                                   b0, b1, b2, W3, b3, partial);
    reduce_kernel<<<NMOL, 256, 0, stream>>>(partial, out);
}

// Round 4
// 56.671 us; speedup vs baseline: 28.3842x; 1.2020x over previous
//
#include <hip/hip_runtime.h>

// ANI-1 per-species MLP, v4: PURE bf16 MFMA (fp32 accumulate), no hi/lo split.
// Per (atom, mol-half): Y = X[64 x K] * W^T, layers 384->160->128->96->1.
// Block = 512 threads (8 waves, 2 M-groups x 4 N-groups), grid = 1024.
// LDS 38 KB -> 4 blocks/CU (32 waves/CU). Error budget: bf16 RTN rounding,
// zero-mean, iid across atoms -> molecule-sum absmax ~0.01-0.05 << 0.152.

typedef float f32x4 __attribute__((ext_vector_type(4)));
typedef short s16x8 __attribute__((ext_vector_type(8)));

#define NMOL   128
#define NATOM  512
#define AEV    384
#define MT     64               // molecules per block

// Wp element offsets (bf16 units), single plane now
#define PL0    61440            // 160*384
#define PL1    20480            // 128*160
#define PL2    12288            // 96*128
#define BASE0  0
#define BASE1  245760           // 4*PL0
#define BASE2  327680           // BASE1 + 4*PL1
#define WP_BYTE_OFF 262144      // partial buffer (512*128*4) comes first in d_ws

__device__ __forceinline__ ushort f2bf(float f) {   // RTN-even
    uint u = __float_as_uint(f);
    return (ushort)((u + 0x7fffu + ((u >> 16) & 1u)) >> 16);
}
__device__ __forceinline__ float bf2f(ushort h) {
    return __uint_as_float(((uint)h) << 16);
}
__device__ __forceinline__ float celu_f(float v) {
    return fmaxf(v, 0.0f) + fminf(0.1f * (__expf(10.0f * v) - 1.0f), 0.0f);
}

// ---- prep: round W0..W2 to bf16 in MFMA-B-fragment order ----
__global__ __launch_bounds__(256) void prep_kernel(
    const float* __restrict__ W0, const float* __restrict__ W1,
    const float* __restrict__ W2, ushort* __restrict__ Wp)
{
    const int idx = blockIdx.x * 256 + threadIdx.x;   // grid sized exactly 376832
    int n, k, KS;
    size_t base;
    float f;
    if (idx < 245760) {                       // L0: [4][160][384]
        const int s = idx / PL0, r = idx % PL0;
        n = r / 384; k = r % 384; KS = 12;
        f = W0[idx];
        base = BASE0 + (size_t)s * PL0;
    } else if (idx < 327680) {                // L1: [4][128][160]
        const int i2 = idx - 245760;
        const int s = i2 / PL1, r = i2 % PL1;
        n = r / 160; k = r % 160; KS = 5;
        f = W1[i2];
        base = BASE1 + (size_t)s * PL1;
    } else {                                  // L2: [4][96][128]
        const int i2 = idx - 327680;
        const int s = i2 / PL2, r = i2 % PL2;
        n = r / 128; k = r % 128; KS = 4;
        f = W2[i2];
        base = BASE2 + (size_t)s * PL2;
    }
    // frag order: lane l holds B[k=(l>>4)*8+j][n=l&15] for (kstep, fragN)
    const size_t fo = (size_t)((((n >> 4) * KS + (k >> 5)) * 64
                                + ((k & 31) >> 3) * 16 + (n & 15)) * 8 + (k & 7));
    Wp[base + fo] = f2bf(f);
}

// ---- generic resident-A layer: M=64 (2 mgrp x 2 frag), N=NF*16, K=KS*32 ----
template <int KS, int NF>
__device__ __forceinline__ void layer_gemm(
    const ushort* __restrict__ Ah, const int lda,
    const ushort* __restrict__ Bh,
    const float* __restrict__ bias,
    ushort* __restrict__ Ch, const int ldc,
    const int mgrp, const int ngrp, const int lane)
{
    f32x4 acc[2][3];
    const f32x4 zero = {0.f, 0.f, 0.f, 0.f};
    #pragma unroll
    for (int mf = 0; mf < 2; ++mf)
        #pragma unroll
        for (int t = 0; t < 3; ++t) acc[mf][t] = zero;

    const int arow  = mgrp * 32 + (lane & 15);
    const int akoff = (lane >> 4) * 8;

    #pragma unroll
    for (int ks = 0; ks < KS; ++ks) {
        s16x8 ah[2];
        #pragma unroll
        for (int mf = 0; mf < 2; ++mf)
            ah[mf] = *(const s16x8*)(Ah + (arow + mf * 16) * lda + ks * 32 + akoff);
        #pragma unroll
        for (int t = 0; t < 3; ++t) {
            const int nf = ngrp + 4 * t;
            if (nf < NF) {
                const s16x8 bh = *(const s16x8*)(Bh + ((nf * KS + ks) * 64 + lane) * 8);
                #pragma unroll
                for (int mf = 0; mf < 2; ++mf)
                    acc[mf][t] = __builtin_amdgcn_mfma_f32_16x16x32_bf16(
                        ah[mf], bh, acc[mf][t], 0, 0, 0);
            }
        }
    }
    // epilogue: bias + CELU + round -> LDS
    #pragma unroll
    for (int t = 0; t < 3; ++t) {
        const int nf = ngrp + 4 * t;
        if (nf < NF) {
            const int n = nf * 16 + (lane & 15);
            const float bv = bias[n];
            #pragma unroll
            for (int mf = 0; mf < 2; ++mf) {
                #pragma unroll
                for (int r = 0; r < 4; ++r) {
                    const int row = mgrp * 32 + mf * 16 + (lane >> 4) * 4 + r;
                    Ch[row * ldc + n] = f2bf(celu_f(acc[mf][t][r] + bv));
                }
            }
        }
    }
}

__global__ __launch_bounds__(512, 8) void ani_mfma_kernel(
    const float* __restrict__ aev, const int* __restrict__ species,
    const ushort* __restrict__ Wp,
    const float* __restrict__ b0, const float* __restrict__ b1,
    const float* __restrict__ b2,
    const float* __restrict__ W3, const float* __restrict__ b3,
    float* __restrict__ partial)
{
    __shared__ __align__(16) ushort xbuf[MT * 136];   // 17408 B: X tile -> Y1 -> red
    __shared__ __align__(16) ushort ybuf[MT * 168];   // 21504 B: Y0 -> Y2

    const int bid  = blockIdx.x;
    const int a    = bid >> 1;          // atom
    const int half = bid & 1;           // which 64-molecule half
    const int tid  = threadIdx.x;
    const int lane = tid & 63;
    const int wid  = tid >> 6;
    const int mgrp = wid >> 2;          // 0..1 (rows mgrp*32 .. +31)
    const int ngrp = wid & 3;           // 0..3
    const int s    = species[a];

    ushort* Xh  = xbuf;
    ushort* Y0h = ybuf;
    ushort* Y1h = xbuf;
    ushort* Y2h = ybuf;

    const ushort* Bh0 = Wp + BASE0 + (size_t)s * PL0;
    const ushort* Bh1 = Wp + BASE1 + (size_t)s * PL1;
    const ushort* Bh2 = Wp + BASE2 + (size_t)s * PL2;
    const float* b0s = b0 + s * 160;
    const float* b1s = b1 + s * 128;
    const float* b2s = b2 + s * 96;
    const float* w3s = W3 + s * 96;
    const float  bb3 = b3[s];

    // ================= L0: 384 -> 160, K-tiled X staging =================
    f32x4 acc[2][3];
    const f32x4 zero = {0.f, 0.f, 0.f, 0.f};
    #pragma unroll
    for (int mf = 0; mf < 2; ++mf)
        #pragma unroll
        for (int t = 0; t < 3; ++t) acc[mf][t] = zero;

    float4 rv[4];
    #pragma unroll
    for (int p = 0; p < 4; ++p) {     // prefetch tile 0: [64 mol][128 k]
        const int ix = tid + p * 512;
        const int gmol = half * MT + (ix >> 5);
        rv[p] = *(const float4*)(aev + ((size_t)gmol * NATOM + a) * AEV + (ix & 31) * 4);
    }

    for (int tile = 0; tile < 3; ++tile) {
        // write staged regs (bf16 round) into LDS
        #pragma unroll
        for (int p = 0; p < 4; ++p) {
            const int ix = tid + p * 512;
            const int mol = ix >> 5, c4 = ix & 31;
            const float4 v = rv[p];
            uint2 ph;
            ph.x = (uint)f2bf(v.x) | ((uint)f2bf(v.y) << 16);
            ph.y = (uint)f2bf(v.z) | ((uint)f2bf(v.w) << 16);
            *(uint2*)(Xh + mol * 136 + c4 * 4) = ph;
        }
        __syncthreads();
        if (tile < 2) {               // prefetch next tile during compute
            #pragma unroll
            for (int p = 0; p < 4; ++p) {
                const int ix = tid + p * 512;
                const int gmol = half * MT + (ix >> 5);
                rv[p] = *(const float4*)(aev + ((size_t)gmol * NATOM + a) * AEV
                                         + (tile + 1) * 128 + (ix & 31) * 4);
            }
        }
        #pragma unroll
        for (int ks = 0; ks < 4; ++ks) {
            const int gks = tile * 4 + ks;
            s16x8 ah[2];
            #pragma unroll
            for (int mf = 0; mf < 2; ++mf) {
                const int ao = (mgrp * 32 + mf * 16 + (lane & 15)) * 136
                               + ks * 32 + (lane >> 4) * 8;
                ah[mf] = *(const s16x8*)(Xh + ao);
            }
            #pragma unroll
            for (int t = 0; t < 3; ++t) {
                const int nf = ngrp + 4 * t;
                if (nf < 10) {
                    const s16x8 bh = *(const s16x8*)(Bh0 + ((nf * 12 + gks) * 64 + lane) * 8);
                    #pragma unroll
                    for (int mf = 0; mf < 2; ++mf)
                        acc[mf][t] = __builtin_amdgcn_mfma_f32_16x16x32_bf16(
                            ah[mf], bh, acc[mf][t], 0, 0, 0);
                }
            }
        }
        __syncthreads();
    }
    // L0 epilogue -> Y0 (ld 168)
    #pragma unroll
    for (int t = 0; t < 3; ++t) {
        const int nf = ngrp + 4 * t;
        if (nf < 10) {
            const int n = nf * 16 + (lane & 15);
            const float bv = b0s[n];
            #pragma unroll
            for (int mf = 0; mf < 2; ++mf) {
                #pragma unroll
                for (int r = 0; r < 4; ++r) {
                    const int row = mgrp * 32 + mf * 16 + (lane >> 4) * 4 + r;
                    Y0h[row * 168 + n] = f2bf(celu_f(acc[mf][t][r] + bv));
                }
            }
        }
    }
    __syncthreads();

    // ================= L1: 160 -> 128 =================
    layer_gemm<5, 8>(Y0h, 168, Bh1, b1s, Y1h, 136, mgrp, ngrp, lane);
    __syncthreads();

    // ================= L2: 128 -> 96 =================
    layer_gemm<4, 6>(Y1h, 136, Bh2, b2s, Y2h, 104, mgrp, ngrp, lane);
    __syncthreads();

    // ================= L3: 96 -> 1 (fp32 vector) =================
    {
        float* red = (float*)xbuf;   // Y1 dead
        const int m = tid & (MT - 1);
        const int q = tid >> 6;      // 0..7, each handles 12 of 96 inputs
        float accv = 0.f;
        #pragma unroll
        for (int ii = 0; ii < 12; ++ii) {
            const int i = q * 12 + ii;
            accv = fmaf(w3s[i], bf2f(Y2h[m * 104 + i]), accv);
        }
        red[q * MT + m] = accv;
        __syncthreads();
        if (tid < MT) {
            float sm = bb3;
            #pragma unroll
            for (int qq = 0; qq < 8; ++qq) sm += red[qq * MT + tid];
            partial[(size_t)a * NMOL + half * MT + tid] = sm;
        }
    }
}

__global__ __launch_bounds__(256) void reduce_kernel(
    const float* __restrict__ partial, float* __restrict__ out)
{
    __shared__ float red[256];
    const int m = blockIdx.x;       // molecule
    const int t = threadIdx.x;
    float sv = partial[(size_t)t * NMOL + m] + partial[(size_t)(t + 256) * NMOL + m];
    red[t] = sv;
    __syncthreads();
    #pragma unroll
    for (int w = 128; w > 0; w >>= 1) {
        if (t < w) red[t] += red[t + w];
        __syncthreads();
    }
    if (t == 0) out[m] = red[0];
}

extern "C" void kernel_launch(void* const* d_in, const int* in_sizes, int n_in,
                              void* d_out, int out_size, void* d_ws, size_t ws_size,
                              hipStream_t stream) {
    const float* aev     = (const float*)d_in[0];
    const int*   species = (const int*)  d_in[1];
    const float* W0 = (const float*)d_in[2];
    const float* b0 = (const float*)d_in[3];
    const float* W1 = (const float*)d_in[4];
    const float* b1 = (const float*)d_in[5];
    const float* W2 = (const float*)d_in[6];
    const float* b2 = (const float*)d_in[7];
    const float* W3 = (const float*)d_in[8];
    const float* b3 = (const float*)d_in[9];
    float* out     = (float*)d_out;
    float* partial = (float*)d_ws;                               // 256 KiB
    ushort* Wp     = (ushort*)((char*)d_ws + WP_BYTE_OFF);       // ~0.75 MiB

    prep_kernel<<<1472, 256, 0, stream>>>(W0, W1, W2, Wp);
    ani_mfma_kernel<<<NATOM * 2, 512, 0, stream>>>(aev, species, Wp,
                                                   b0, b1, b2, W3, b3, partial);
    reduce_kernel<<<NMOL, 256, 0, stream>>>(partial, out);
}

// Round 5
// 43.048 us; speedup vs baseline: 37.3660x; 1.3164x over previous
//
#include <hip/hip_runtime.h>

// ANI-1 per-species MLP, v5: bf16 MFMA + register-preloaded B fragments +
// LDS-double-buffered X staging. Fix for v4's register starvation (VGPR=32):
// launch_bounds(512,4) -> ~110 VGPR, loads pipelined instead of serialized.
// Block = 512 threads (8 waves: 2 M-grp x 4 N-grp), grid = 1024 (atom, half).

typedef float f32x4 __attribute__((ext_vector_type(4)));
typedef short s16x8 __attribute__((ext_vector_type(8)));

#define NMOL   128
#define NATOM  512
#define AEV    384
#define MT     64               // molecules (rows) per block
#define XLD    136
#define Y0LD   168
#define Y1LD   136
#define Y2LD   104

// Wp element offsets (bf16 units)
#define PL0    61440            // 160*384
#define PL1    20480            // 128*160
#define PL2    12288            // 96*128
#define BASE0  0
#define BASE1  245760           // 4*PL0
#define BASE2  327680           // BASE1 + 4*PL1
#define WP_BYTE_OFF 262144      // partial buffer (512*128*4) first in d_ws

__device__ __forceinline__ ushort f2bf(float f) {   // RTN-even
    uint u = __float_as_uint(f);
    return (ushort)((u + 0x7fffu + ((u >> 16) & 1u)) >> 16);
}
__device__ __forceinline__ float bf2f(ushort h) {
    return __uint_as_float(((uint)h) << 16);
}
__device__ __forceinline__ float celu_f(float v) {
    return fmaxf(v, 0.0f) + fminf(0.1f * (__expf(10.0f * v) - 1.0f), 0.0f);
}

// ---- prep: round W0..W2 to bf16 in MFMA-B-fragment order ----
__global__ __launch_bounds__(256) void prep_kernel(
    const float* __restrict__ W0, const float* __restrict__ W1,
    const float* __restrict__ W2, ushort* __restrict__ Wp)
{
    const int idx = blockIdx.x * 256 + threadIdx.x;   // grid = 376832
    int n, k, KS;
    size_t base;
    float f;
    if (idx < 245760) {                       // L0: [4][160][384]
        const int s = idx / PL0, r = idx % PL0;
        n = r / 384; k = r % 384; KS = 12;
        f = W0[idx];
        base = BASE0 + (size_t)s * PL0;
    } else if (idx < 327680) {                // L1: [4][128][160]
        const int i2 = idx - 245760;
        const int s = i2 / PL1, r = i2 % PL1;
        n = r / 160; k = r % 160; KS = 5;
        f = W1[i2];
        base = BASE1 + (size_t)s * PL1;
    } else {                                  // L2: [4][96][128]
        const int i2 = idx - 327680;
        const int s = i2 / PL2, r = i2 % PL2;
        n = r / 128; k = r % 128; KS = 4;
        f = W2[i2];
        base = BASE2 + (size_t)s * PL2;
    }
    const size_t fo = (size_t)((((n >> 4) * KS + (k >> 5)) * 64
                                + ((k & 31) >> 3) * 16 + (n & 15)) * 8 + (k & 7));
    Wp[base + fo] = f2bf(f);
}

__global__ __launch_bounds__(512, 4) void ani_mfma_kernel(
    const float* __restrict__ aev, const int* __restrict__ species,
    const ushort* __restrict__ Wp,
    const float* __restrict__ b0, const float* __restrict__ b1,
    const float* __restrict__ b2,
    const float* __restrict__ W3, const float* __restrict__ b3,
    float* __restrict__ partial)
{
    __shared__ __align__(16) ushort xbuf[2 * MT * XLD];   // 34816 B: X dbuf -> Y1 -> red
    __shared__ __align__(16) ushort ybuf[MT * Y0LD];      // 21504 B: Y0 -> Y2

    const int bid  = blockIdx.x;
    const int a    = bid >> 1;
    const int half = bid & 1;
    const int tid  = threadIdx.x;
    const int lane = tid & 63;
    const int wid  = tid >> 6;
    const int mgrp = wid >> 2;          // 0..1
    const int ngrp = wid & 3;           // 0..3
    const bool has3 = (ngrp < 2);       // third N-frag valid (L0 nf=ngrp+8<10; L2 nf=ngrp+4<6)

    // ---- X prefetch plumbing: thread covers mols mol0+16p, fixed c4 ----
    const int mol0 = tid >> 5;          // 0..15
    const int c4   = tid & 31;          // float4 index within 128-k tile
    const float*  xp   = aev + ((size_t)(half * MT + mol0) * NATOM + a) * AEV + c4 * 4;
    const size_t  PSTR = (size_t)16 * NATOM * AEV;

    float4 rv[4];
    #pragma unroll
    for (int p = 0; p < 4; ++p) rv[p] = *(const float4*)(xp + p * PSTR);   // tile0

    const int s = species[a];
    const ushort* Bh0 = Wp + BASE0 + (size_t)s * PL0;
    const ushort* Bh1 = Wp + BASE1 + (size_t)s * PL1;
    const ushort* Bh2 = Wp + BASE2 + (size_t)s * PL2;
    const float* b0s = b0 + s * 160;
    const float* b1s = b1 + s * 128;
    const float* b2s = b2 + s * 96;
    const float* w3s = W3 + s * 96;
    const float  bb3 = b3[s];

    ushort* X0 = xbuf;
    ushort* X1 = xbuf + MT * XLD;

    auto stage = [&](ushort* dst) {
        #pragma unroll
        for (int p = 0; p < 4; ++p) {
            uint2 ph;
            ph.x = (uint)f2bf(rv[p].x) | ((uint)f2bf(rv[p].y) << 16);
            ph.y = (uint)f2bf(rv[p].z) | ((uint)f2bf(rv[p].w) << 16);
            *(uint2*)(dst + (mol0 + 16 * p) * XLD + c4 * 4) = ph;
        }
    };

    s16x8 bl[3][4];   // B frags for current L0 tile: [t][ks], t=2 only if has3
    auto l0_bload = [&](int tile) {
        #pragma unroll
        for (int ks = 0; ks < 4; ++ks) {
            const int gks = tile * 4 + ks;
            bl[0][ks] = *(const s16x8*)(Bh0 + ((size_t)((ngrp     ) * 12 + gks) * 64 + lane) * 8);
            bl[1][ks] = *(const s16x8*)(Bh0 + ((size_t)((ngrp +  4) * 12 + gks) * 64 + lane) * 8);
        }
        if (has3) {
            #pragma unroll
            for (int ks = 0; ks < 4; ++ks) {
                const int gks = tile * 4 + ks;
                bl[2][ks] = *(const s16x8*)(Bh0 + ((size_t)((ngrp + 8) * 12 + gks) * 64 + lane) * 8);
            }
        }
    };

    f32x4 acc[2][3];
    const f32x4 zero = {0.f, 0.f, 0.f, 0.f};
    #pragma unroll
    for (int mf = 0; mf < 2; ++mf)
        #pragma unroll
        for (int t = 0; t < 3; ++t) acc[mf][t] = zero;

    auto l0_tile = [&](const ushort* Xb) {
        #pragma unroll
        for (int ks = 0; ks < 4; ++ks) {
            s16x8 ah[2];
            #pragma unroll
            for (int mf = 0; mf < 2; ++mf)
                ah[mf] = *(const s16x8*)(Xb + (mgrp * 32 + mf * 16 + (lane & 15)) * XLD
                                         + ks * 32 + (lane >> 4) * 8);
            #pragma unroll
            for (int mf = 0; mf < 2; ++mf) {
                acc[mf][0] = __builtin_amdgcn_mfma_f32_16x16x32_bf16(ah[mf], bl[0][ks], acc[mf][0], 0, 0, 0);
                acc[mf][1] = __builtin_amdgcn_mfma_f32_16x16x32_bf16(ah[mf], bl[1][ks], acc[mf][1], 0, 0, 0);
            }
            if (has3) {
                #pragma unroll
                for (int mf = 0; mf < 2; ++mf)
                    acc[mf][2] = __builtin_amdgcn_mfma_f32_16x16x32_bf16(ah[mf], bl[2][ks], acc[mf][2], 0, 0, 0);
            }
        }
    };

    // ---- L0 pipeline: stage(t) | bload(t) | prefetch rv(t+1) | barrier | compute(t) ...
    stage(X0);                    // waits rv(t0) only
    l0_bload(0);                  // in flight across barrier
    #pragma unroll
    for (int p = 0; p < 4; ++p) rv[p] = *(const float4*)(xp + 128 + p * PSTR);   // tile1
    __syncthreads();

    l0_tile(X0);                  // waits bl(t0); rv(t1) keeps flying (younger)
    l0_bload(1);
    stage(X1);                    // waits rv(t1); bl(t1) younger, keeps flying
    #pragma unroll
    for (int p = 0; p < 4; ++p) rv[p] = *(const float4*)(xp + 256 + p * PSTR);   // tile2
    __syncthreads();

    l0_tile(X1);
    l0_bload(2);
    stage(X0);                    // waits rv(t2)
    __syncthreads();

    l0_tile(X0);

    // L1 B preload: issue now, flies during L0 epilogue + barrier
    s16x8 b1r[2][5];
    #pragma unroll
    for (int ks = 0; ks < 5; ++ks) {
        b1r[0][ks] = *(const s16x8*)(Bh1 + ((size_t)((ngrp    ) * 5 + ks) * 64 + lane) * 8);
        b1r[1][ks] = *(const s16x8*)(Bh1 + ((size_t)((ngrp + 4) * 5 + ks) * 64 + lane) * 8);
    }

    // ---- L0 epilogue -> Y0 (ld 168) ----
    #pragma unroll
    for (int t = 0; t < 3; ++t) {
        if (t < 2 || has3) {
            const int n = (ngrp + 4 * t) * 16 + (lane & 15);
            const float bv = b0s[n];
            #pragma unroll
            for (int mf = 0; mf < 2; ++mf) {
                #pragma unroll
                for (int r = 0; r < 4; ++r) {
                    const int row = mgrp * 32 + mf * 16 + (lane >> 4) * 4 + r;
                    ybuf[row * Y0LD + n] = f2bf(celu_f(acc[mf][t][r] + bv));
                }
            }
        }
    }
    __syncthreads();

    // ---- L1: 160 -> 128 (A from Y0/ybuf, C -> Y1/xbuf) ----
    f32x4 acc1[2][2];
    #pragma unroll
    for (int mf = 0; mf < 2; ++mf) { acc1[mf][0] = zero; acc1[mf][1] = zero; }
    #pragma unroll
    for (int ks = 0; ks < 5; ++ks) {
        s16x8 ah[2];
        #pragma unroll
        for (int mf = 0; mf < 2; ++mf)
            ah[mf] = *(const s16x8*)(ybuf + (mgrp * 32 + mf * 16 + (lane & 15)) * Y0LD
                                     + ks * 32 + (lane >> 4) * 8);
        #pragma unroll
        for (int mf = 0; mf < 2; ++mf) {
            acc1[mf][0] = __builtin_amdgcn_mfma_f32_16x16x32_bf16(ah[mf], b1r[0][ks], acc1[mf][0], 0, 0, 0);
            acc1[mf][1] = __builtin_amdgcn_mfma_f32_16x16x32_bf16(ah[mf], b1r[1][ks], acc1[mf][1], 0, 0, 0);
        }
    }

    // L2 B preload: flies during L1 epilogue + barrier
    s16x8 b2r[2][4];
    #pragma unroll
    for (int ks = 0; ks < 4; ++ks)
        b2r[0][ks] = *(const s16x8*)(Bh2 + ((size_t)((ngrp) * 4 + ks) * 64 + lane) * 8);
    if (has3) {
        #pragma unroll
        for (int ks = 0; ks < 4; ++ks)
            b2r[1][ks] = *(const s16x8*)(Bh2 + ((size_t)((ngrp + 4) * 4 + ks) * 64 + lane) * 8);
    }

    // ---- L1 epilogue -> Y1 (xbuf, ld 136) ----
    ushort* Y1h = xbuf;
    #pragma unroll
    for (int t = 0; t < 2; ++t) {
        const int n = (ngrp + 4 * t) * 16 + (lane & 15);
        const float bv = b1s[n];
        #pragma unroll
        for (int mf = 0; mf < 2; ++mf) {
            #pragma unroll
            for (int r = 0; r < 4; ++r) {
                const int row = mgrp * 32 + mf * 16 + (lane >> 4) * 4 + r;
                Y1h[row * Y1LD + n] = f2bf(celu_f(acc1[mf][t][r] + bv));
            }
        }
    }
    __syncthreads();

    // ---- L2: 128 -> 96 (A from Y1/xbuf, C -> Y2/ybuf ld 104) ----
    f32x4 acc2[2][2];
    #pragma unroll
    for (int mf = 0; mf < 2; ++mf) { acc2[mf][0] = zero; acc2[mf][1] = zero; }
    #pragma unroll
    for (int ks = 0; ks < 4; ++ks) {
        s16x8 ah[2];
        #pragma unroll
        for (int mf = 0; mf < 2; ++mf)
            ah[mf] = *(const s16x8*)(Y1h + (mgrp * 32 + mf * 16 + (lane & 15)) * Y1LD
                                     + ks * 32 + (lane >> 4) * 8);
        #pragma unroll
        for (int mf = 0; mf < 2; ++mf) {
            acc2[mf][0] = __builtin_amdgcn_mfma_f32_16x16x32_bf16(ah[mf], b2r[0][ks], acc2[mf][0], 0, 0, 0);
            if (has3)
                acc2[mf][1] = __builtin_amdgcn_mfma_f32_16x16x32_bf16(ah[mf], b2r[1][ks], acc2[mf][1], 0, 0, 0);
        }
    }

    // ---- L2 epilogue -> Y2 (ybuf, ld 104) ----
    ushort* Y2h = ybuf;
    #pragma unroll
    for (int t = 0; t < 2; ++t) {
        if (t == 0 || has3) {
            const int n = (ngrp + 4 * t) * 16 + (lane & 15);   // < 96
            const float bv = b2s[n];
            #pragma unroll
            for (int mf = 0; mf < 2; ++mf) {
                #pragma unroll
                for (int r = 0; r < 4; ++r) {
                    const int row = mgrp * 32 + mf * 16 + (lane >> 4) * 4 + r;
                    Y2h[row * Y2LD + n] = f2bf(celu_f(acc2[mf][t][r] + bv));
                }
            }
        }
    }
    __syncthreads();

    // ---- L3: 96 -> 1 (fp32 vector) ----
    {
        float* red = (float*)xbuf;   // Y1 dead
        const int m = tid & (MT - 1);
        const int q = tid >> 6;      // 0..7, 12 inputs each
        float accv = 0.f;
        #pragma unroll
        for (int ii = 0; ii < 12; ++ii) {
            const int i = q * 12 + ii;
            accv = fmaf(w3s[i], bf2f(Y2h[m * Y2LD + i]), accv);
        }
        red[q * MT + m] = accv;
        __syncthreads();
        if (tid < MT) {
            float sm = bb3;
            #pragma unroll
            for (int qq = 0; qq < 8; ++qq) sm += red[qq * MT + tid];
            partial[(size_t)a * NMOL + half * MT + tid] = sm;
        }
    }
}

__global__ __launch_bounds__(256) void reduce_kernel(
    const float* __restrict__ partial, float* __restrict__ out)
{
    __shared__ float red[256];
    const int m = blockIdx.x;       // molecule
    const int t = threadIdx.x;
    float sv = partial[(size_t)t * NMOL + m] + partial[(size_t)(t + 256) * NMOL + m];
    red[t] = sv;
    __syncthreads();
    #pragma unroll
    for (int w = 128; w > 0; w >>= 1) {
        if (t < w) red[t] += red[t + w];
        __syncthreads();
    }
    if (t == 0) out[m] = red[0];
}

extern "C" void kernel_launch(void* const* d_in, const int* in_sizes, int n_in,
                              void* d_out, int out_size, void* d_ws, size_t ws_size,
                              hipStream_t stream) {
    const float* aev     = (const float*)d_in[0];
    const int*   species = (const int*)  d_in[1];
    const float* W0 = (const float*)d_in[2];
    const float* b0 = (const float*)d_in[3];
    const float* W1 = (const float*)d_in[4];
    const float* b1 = (const float*)d_in[5];
    const float* W2 = (const float*)d_in[6];
    const float* b2 = (const float*)d_in[7];
    const float* W3 = (const float*)d_in[8];
    const float* b3 = (const float*)d_in[9];
    float* out     = (float*)d_out;
    float* partial = (float*)d_ws;                               // 256 KiB
    ushort* Wp     = (ushort*)((char*)d_ws + WP_BYTE_OFF);       // ~0.75 MiB

    prep_kernel<<<1472, 256, 0, stream>>>(W0, W1, W2, Wp);
    ani_mfma_kernel<<<NATOM * 2, 512, 0, stream>>>(aev, species, Wp,
                                                   b0, b1, b2, W3, b3, partial);
    reduce_kernel<<<NMOL, 256, 0, stream>>>(partial, out);
}